// Round 1
// baseline (2112.370 us; speedup 1.0000x reference)
//
#include <hip/hip_runtime.h>

#define N 8192
#define ITERS 50
#define ROWS 8   // rows per block

// ws layout (floats): [0..N) bufA, [N..2N) bufB, [2N..2N+ITERS+1) normsq
__global__ void pi_init_kernel(float* __restrict__ bufA, float* __restrict__ nsq) {
    int i = blockIdx.x * blockDim.x + threadIdx.x;
    if (i < N) bufA[i] = 1.0f;                 // v0 = ones
    if (i <= ITERS) nsq[i] = (i == 0) ? 1.0f : 0.0f;
}

// One GEMV step: vout = (M @ vin) * rsqrt(*nsq_prev); atomically accumulate
// sum(vout^2) into *nsq_next. vin is the UNNORMALIZED previous result; the
// scale folds the previous normalization in: M(v/c) = (Mv)/c.
__global__ __launch_bounds__(256) void pi_gemv_kernel(
        const float4* __restrict__ M4,
        const float4* __restrict__ vin4,
        float* __restrict__ vout,
        const float* __restrict__ nsq_prev,
        float* __restrict__ nsq_next) {
    const int t = threadIdx.x;
    const int row0 = blockIdx.x * ROWS;
    const float s = rsqrtf(*nsq_prev);

    constexpr int NV = N / 4;          // 2048 float4 per row
    constexpr int CHUNKS = NV / 256;   // 8 chunks per row

    float acc[ROWS];
#pragma unroll
    for (int r = 0; r < ROWS; ++r) acc[r] = 0.0f;

    for (int c = 0; c < CHUNKS; ++c) {
        const int idx = c * 256 + t;   // coalesced: lane i -> consecutive float4
        const float4 vv = vin4[idx];
#pragma unroll
        for (int r = 0; r < ROWS; ++r) {
            const float4 m = M4[(size_t)(row0 + r) * NV + idx];
            acc[r] += m.x * vv.x + m.y * vv.y + m.z * vv.z + m.w * vv.w;
        }
    }

    // 64-lane tree reduction per row
#pragma unroll
    for (int r = 0; r < ROWS; ++r) {
        float a = acc[r];
        for (int off = 32; off > 0; off >>= 1) a += __shfl_down(a, off, 64);
        acc[r] = a;                    // valid on lane 0 of each wave
    }

    __shared__ float part[4][ROWS];
    const int wave = t >> 6, lane = t & 63;
    if (lane == 0) {
#pragma unroll
        for (int r = 0; r < ROWS; ++r) part[wave][r] = acc[r];
    }
    __syncthreads();

    float sq = 0.0f;
    if (t < ROWS) {
        const float sum = part[0][t] + part[1][t] + part[2][t] + part[3][t];
        const float y = sum * s;
        vout[row0 + t] = y;
        sq = y * y;
    }
    // reduce sq over wave 0 (all ROWS<=64 finalists live in wave 0)
    if (wave == 0) {
        for (int off = 32; off > 0; off >>= 1) sq += __shfl_down(sq, off, 64);
        if (lane == 0) atomicAdd(nsq_next, sq);
    }
}

__global__ void pi_scale_kernel(const float* __restrict__ vin,
                                const float* __restrict__ nsq,
                                float* __restrict__ out) {
    int i = blockIdx.x * blockDim.x + threadIdx.x;
    const float s = rsqrtf(*nsq);
    if (i < N) out[i] = vin[i] * s;
}

extern "C" void kernel_launch(void* const* d_in, const int* in_sizes, int n_in,
                              void* d_out, int out_size, void* d_ws, size_t ws_size,
                              hipStream_t stream) {
    const float* M = (const float*)d_in[0];
    float* out = (float*)d_out;
    float* ws = (float*)d_ws;

    float* bufA = ws;            // u_k for even k (u_0 = ones)
    float* bufB = ws + N;        // u_k for odd k
    float* nsq  = ws + 2 * N;    // normsq[0..ITERS], normsq[0] = 1.0

    pi_init_kernel<<<(N + 255) / 256, 256, 0, stream>>>(bufA, nsq);

    const float4* M4 = (const float4*)M;
    for (int k = 1; k <= ITERS; ++k) {
        const float* vin = (k & 1) ? bufA : bufB;
        float* vout      = (k & 1) ? bufB : bufA;
        pi_gemv_kernel<<<N / ROWS, 256, 0, stream>>>(
            M4, (const float4*)vin, vout, nsq + (k - 1), nsq + k);
    }
    // ITERS=50 is even -> final unnormalized vector is in bufA
    pi_scale_kernel<<<(N + 255) / 256, 256, 0, stream>>>(bufA, nsq + ITERS, out);
}

// Round 2
// 2046.763 us; speedup vs baseline: 1.0321x; 1.0321x over previous
//
#include <hip/hip_runtime.h>

#define N 8192
#define ITERS 50
#define ROWS 8   // rows per block

typedef unsigned int uint32;

// ---------------------------------------------------------------------------
// init: v0 = ones, nsq[0] = 1, nsq[1..ITERS] = 0
// ---------------------------------------------------------------------------
__global__ void pi_init_kernel(float* __restrict__ bufA, float* __restrict__ nsq) {
    int i = blockIdx.x * blockDim.x + threadIdx.x;
    if (i < N) bufA[i] = 1.0f;
    if (i <= ITERS) nsq[i] = (i == 0) ? 1.0f : 0.0f;
}

// ---------------------------------------------------------------------------
// shared epilogue: per-row wave reduce -> cross-wave via LDS -> write vout,
// accumulate sum(vout^2) into nsq_next
// ---------------------------------------------------------------------------
__device__ __forceinline__ void pi_epilogue(float (&acc)[ROWS], int t, int row0,
                                            float s, float* __restrict__ vout,
                                            float* __restrict__ nsq_next) {
#pragma unroll
    for (int r = 0; r < ROWS; ++r) {
        float a = acc[r];
        for (int off = 32; off > 0; off >>= 1) a += __shfl_down(a, off, 64);
        acc[r] = a;
    }
    __shared__ float part[4][ROWS];
    const int wave = t >> 6, lane = t & 63;
    if (lane == 0) {
#pragma unroll
        for (int r = 0; r < ROWS; ++r) part[wave][r] = acc[r];
    }
    __syncthreads();
    float sq = 0.0f;
    if (t < ROWS) {
        const float sum = part[0][t] + part[1][t] + part[2][t] + part[3][t];
        const float y = sum * s;
        vout[row0 + t] = y;
        sq = y * y;
    }
    if (wave == 0) {
        for (int off = 32; off > 0; off >>= 1) sq += __shfl_down(sq, off, 64);
        if (lane == 0) atomicAdd(nsq_next, sq);
    }
}

// ---------------------------------------------------------------------------
// fp32 GEMV (fallback path + used as iter-1 when fused w/ conversion below)
// ---------------------------------------------------------------------------
__global__ __launch_bounds__(256) void pi_gemv_kernel(
        const float4* __restrict__ M4,
        const float4* __restrict__ vin4,
        float* __restrict__ vout,
        const float* __restrict__ nsq_prev,
        float* __restrict__ nsq_next) {
    const int t = threadIdx.x;
    const int row0 = blockIdx.x * ROWS;
    const float s = rsqrtf(*nsq_prev);
    constexpr int NV = N / 4;
    constexpr int CHUNKS = NV / 256;
    float acc[ROWS];
#pragma unroll
    for (int r = 0; r < ROWS; ++r) acc[r] = 0.0f;
    for (int c = 0; c < CHUNKS; ++c) {
        const int idx = c * 256 + t;
        const float4 vv = vin4[idx];
#pragma unroll
        for (int r = 0; r < ROWS; ++r) {
            const float4 m = M4[(size_t)(row0 + r) * NV + idx];
            acc[r] += m.x * vv.x + m.y * vv.y + m.z * vv.z + m.w * vv.w;
        }
    }
    pi_epilogue(acc, t, row0, s, vout, nsq_next);
}

// ---------------------------------------------------------------------------
// iter 1 fused with conversion: read fp32 M, do GEMV, and write 3-byte planes:
//   hi: bits[31:16] (ushort), lo: bits[15:8] (uchar), round-to-nearest (+0x80)
// hi packed as uint2 per float4 (4 ushorts), lo packed as uint per float4.
// ---------------------------------------------------------------------------
__global__ __launch_bounds__(256) void pi_gemv_convert_kernel(
        const float4* __restrict__ M4,
        const float4* __restrict__ vin4,
        float* __restrict__ vout,
        const float* __restrict__ nsq_prev,
        float* __restrict__ nsq_next,
        uint2* __restrict__ hi2,     // N*N/4 uint2, row stride N/4
        uint32* __restrict__ lo1) {  // N*N/4 uint,  row stride N/4
    const int t = threadIdx.x;
    const int row0 = blockIdx.x * ROWS;
    const float s = rsqrtf(*nsq_prev);
    constexpr int NV = N / 4;
    constexpr int CHUNKS = NV / 256;
    float acc[ROWS];
#pragma unroll
    for (int r = 0; r < ROWS; ++r) acc[r] = 0.0f;
    for (int c = 0; c < CHUNKS; ++c) {
        const int idx = c * 256 + t;
        const float4 vv = vin4[idx];
#pragma unroll
        for (int r = 0; r < ROWS; ++r) {
            const size_t off = (size_t)(row0 + r) * NV + idx;
            const float4 m = M4[off];
            acc[r] += m.x * vv.x + m.y * vv.y + m.z * vv.z + m.w * vv.w;
            // round-to-nearest on dropped low byte
            const uint32 u0 = __float_as_uint(m.x) + 0x80u;
            const uint32 u1 = __float_as_uint(m.y) + 0x80u;
            const uint32 u2 = __float_as_uint(m.z) + 0x80u;
            const uint32 u3 = __float_as_uint(m.w) + 0x80u;
            uint2 h;
            h.x = (u0 >> 16) | (u1 & 0xFFFF0000u);
            h.y = (u2 >> 16) | (u3 & 0xFFFF0000u);
            const uint32 l = ((u0 >> 8) & 0xFFu)        | (((u1 >> 8) & 0xFFu) << 8) |
                             (((u2 >> 8) & 0xFFu) << 16) | (((u3 >> 8) & 0xFFu) << 24);
            hi2[off] = h;
            lo1[off] = l;
        }
    }
    pi_epilogue(acc, t, row0, s, vout, nsq_next);
}

// ---------------------------------------------------------------------------
// 3-byte GEMV: decode f32 = (hi<<16)|(lo<<8), 8 elements per step
// ---------------------------------------------------------------------------
__device__ __forceinline__ void dec4(uint32 h01, uint32 h23, uint32 l, float4& f) {
    f.x = __uint_as_float((h01 << 16)        | ((l & 0x000000FFu) << 8));
    f.y = __uint_as_float((h01 & 0xFFFF0000u) | (l & 0x0000FF00u));
    f.z = __uint_as_float((h23 << 16)        | ((l >> 8) & 0x0000FF00u));
    f.w = __uint_as_float((h23 & 0xFFFF0000u) | ((l >> 16) & 0x0000FF00u));
}

__global__ __launch_bounds__(256) void pi_gemv3_kernel(
        const uint4* __restrict__ hi4,   // 8 ushorts per load, row stride N/8
        const uint2* __restrict__ lo2,   // 8 uchars per load, row stride N/8
        const float4* __restrict__ vin4,
        float* __restrict__ vout,
        const float* __restrict__ nsq_prev,
        float* __restrict__ nsq_next) {
    const int t = threadIdx.x;
    const int row0 = blockIdx.x * ROWS;
    const float s = rsqrtf(*nsq_prev);
    constexpr int NG = N / 8;          // 1024 groups per row
    constexpr int CHUNKS = NG / 256;   // 4
    float acc[ROWS];
#pragma unroll
    for (int r = 0; r < ROWS; ++r) acc[r] = 0.0f;
    for (int c = 0; c < CHUNKS; ++c) {
        const int idx = c * 256 + t;
        const float4 va = vin4[2 * idx];
        const float4 vb = vin4[2 * idx + 1];
#pragma unroll
        for (int r = 0; r < ROWS; ++r) {
            const size_t off = (size_t)(row0 + r) * NG + idx;
            const uint4 h = hi4[off];
            const uint2 l = lo2[off];
            float4 f0, f1;
            dec4(h.x, h.y, l.x, f0);
            dec4(h.z, h.w, l.y, f1);
            acc[r] += f0.x * va.x + f0.y * va.y + f0.z * va.z + f0.w * va.w +
                      f1.x * vb.x + f1.y * vb.y + f1.z * vb.z + f1.w * vb.w;
        }
    }
    pi_epilogue(acc, t, row0, s, vout, nsq_next);
}

__global__ void pi_scale_kernel(const float* __restrict__ vin,
                                const float* __restrict__ nsq,
                                float* __restrict__ out) {
    int i = blockIdx.x * blockDim.x + threadIdx.x;
    const float s = rsqrtf(*nsq);
    if (i < N) out[i] = vin[i] * s;
}

extern "C" void kernel_launch(void* const* d_in, const int* in_sizes, int n_in,
                              void* d_out, int out_size, void* d_ws, size_t ws_size,
                              hipStream_t stream) {
    const float* M = (const float*)d_in[0];
    float* out = (float*)d_out;

    const size_t HI_BYTES = (size_t)N * N * 2;   // 128 MiB
    const size_t LO_BYTES = (size_t)N * N;       //  64 MiB
    const size_t VEC_BYTES = (size_t)(2 * N + ITERS + 1) * sizeof(float);
    const bool use3 = (ws_size >= HI_BYTES + LO_BYTES + VEC_BYTES);

    char* ws = (char*)d_ws;
    float* bufA;
    float* bufB;
    float* nsq;
    uint32* hi = nullptr;
    uint32* lo = nullptr;
    if (use3) {
        hi   = (uint32*)ws;                        // 16B-aligned (ws base)
        lo   = (uint32*)(ws + HI_BYTES);
        bufA = (float*)(ws + HI_BYTES + LO_BYTES);
        bufB = bufA + N;
        nsq  = bufB + N;
    } else {
        bufA = (float*)ws;
        bufB = bufA + N;
        nsq  = bufB + N;
    }

    pi_init_kernel<<<(N + 255) / 256, 256, 0, stream>>>(bufA, nsq);

    const float4* M4 = (const float4*)M;
    if (use3) {
        // iter 1: fp32 GEMV fused with 3-byte conversion
        pi_gemv_convert_kernel<<<N / ROWS, 256, 0, stream>>>(
            M4, (const float4*)bufA, bufB, nsq, nsq + 1,
            (uint2*)hi, lo);
        // iters 2..50: 3-byte GEMV
        for (int k = 2; k <= ITERS; ++k) {
            const float* vin = (k & 1) ? bufA : bufB;
            float* vout      = (k & 1) ? bufB : bufA;
            pi_gemv3_kernel<<<N / ROWS, 256, 0, stream>>>(
                (const uint4*)hi, (const uint2*)lo,
                (const float4*)vin, vout, nsq + (k - 1), nsq + k);
        }
    } else {
        for (int k = 1; k <= ITERS; ++k) {
            const float* vin = (k & 1) ? bufA : bufB;
            float* vout      = (k & 1) ? bufB : bufA;
            pi_gemv_kernel<<<N / ROWS, 256, 0, stream>>>(
                M4, (const float4*)vin, vout, nsq + (k - 1), nsq + k);
        }
    }
    // ITERS even -> final unnormalized vector in bufA
    pi_scale_kernel<<<(N + 255) / 256, 256, 0, stream>>>(bufA, nsq + ITERS, out);
}